// Round 10
// baseline (167.903 us; speedup 1.0000x reference)
//
#include <hip/hip_runtime.h>
#include <hip/hip_bf16.h>
#include <math.h>

#define NH 8
#define HS 64
#define VOCAB 16384
#define QPH 2048                         // queries per head = b(4) * t(512)
#define NSLICE 32                        // vocab slices (512 rows each)
// fold 1/sqrt(512) * log2(e) into Q so the epilogue is p = exp2(score)
#define QSCALE (0.04419417382415922f * 1.4426950408889634f)

typedef __attribute__((ext_vector_type(8))) short bf16x8;
typedef __attribute__((ext_vector_type(4))) float f32x4;

static __device__ __forceinline__ unsigned short f2bf(float f) {
    __hip_bfloat16 h = __float2bfloat16(f);
    unsigned short u;
    __builtin_memcpy(&u, &h, 2);
    return u;
}

static __device__ __forceinline__ float fexp2(float x) {
#if __has_builtin(__builtin_amdgcn_exp2f)
    return __builtin_amdgcn_exp2f(x);     // v_exp_f32 directly
#else
    return __expf(x * 0.6931471805599453f);
#endif
}

// ---------------- Kernel 1: fused prep -----------------------------------------------
// blocks [0,8192):   E -> bf16 cast + g[n][v] = E[n][v,:] . dec_w[n*64:]
// blocks [8192,12288): Q = LayerNorm(enc(x) + PE) * QSCALE -> bf16, wave per row
__global__ void prep(const float* __restrict__ x, const float* __restrict__ emb,
                     const float* __restrict__ enc_w, const float* __restrict__ enc_b,
                     const float* __restrict__ ln_w, const float* __restrict__ ln_b,
                     const float* __restrict__ dec_w,
                     unsigned short* __restrict__ qbf, unsigned short* __restrict__ ebf,
                     float* __restrict__ g) {
    if (blockIdx.x < 8192) {
        int i4  = blockIdx.x * 256 + threadIdx.x;   // float4 index, total 2097152
        int row = i4 >> 4;                          // (n, v) row
        int c   = i4 & 15;
        int n   = row >> 14;
        f32x4 v = ((const f32x4*)emb)[i4];
        ushort4 u = make_ushort4(f2bf(v.x), f2bf(v.y), f2bf(v.z), f2bf(v.w));
        ((ushort4*)ebf)[i4] = u;
        const float* dw = dec_w + n * 64 + c * 4;
        float p = v.x * dw[0] + v.y * dw[1] + v.z * dw[2] + v.w * dw[3];
        p += __shfl_xor(p, 1); p += __shfl_xor(p, 2);
        p += __shfl_xor(p, 4); p += __shfl_xor(p, 8);
        if (c == 0) g[row] = p;
    } else {
        int row  = (blockIdx.x - 8192) * 4 + (threadIdx.x >> 6);  // n*2048 + q
        int h    = threadIdx.x & 63;
        int n = row >> 11;
        int q = row & 2047;
        int t = q & 511;
        float xv = x[q];
        int d = n * 64 + h;
        float h2  = (float)(h & ~1);
        float div = __expf(h2 * (-9.210340371976184f / 64.0f));
        float ang = (float)t * div;
        float pe  = (h & 1) ? __cosf(ang) : __sinf(ang);
        float v = xv * enc_w[d] + enc_b[d] + pe;
        float s = v;
        #pragma unroll
        for (int off = 1; off < 64; off <<= 1) s += __shfl_xor(s, off);
        float mu = s * (1.0f / 64.0f);
        float dd = v - mu;
        float s2 = dd * dd;
        #pragma unroll
        for (int off = 1; off < 64; off <<= 1) s2 += __shfl_xor(s2, off);
        float var = s2 * (1.0f / 64.0f);
        float y = dd * rsqrtf(var + 1e-5f) * ln_w[h] + ln_b[h];
        qbf[row * 64 + h] = f2bf(y * QSCALE);
    }
}

// ---------------- Kernel 2: attn -----------------------------------------------------
// grid 512 = qchunk(2)*256 + vslice(32)*8 + head(8); block 256 (4 waves).
// blockIdx % 8 == head: each XCD's share touches ONE head's E (2MB < 4MB L2).
// Wave w: 256 q (16 MFMA q-tiles, full Q row-block persistent: 128 VGPR) x
// 512-row vocab slice, trip-16 K-loop (unroll disabled).
// SCALING LAW (R3/R6/R8/R9): duration ~= VALU-floor(~26us) + k * per-wave E
// traffic; reorganizing waves at constant traffic is a no-op (R8). Each q/wave
// doubling halves E traffic: 32q=143, 64q=82, 128q=60.6, now 256q.
// CODEGEN NOTES (hard-won):
//  - __launch_bounds__(256,2): ~190-230 VGPR live; tighter caps spill Q frags
//    to scratch (R4: WRITE 4MB->1.5GB). Watch WRITE_SIZE ~4MB == healthy.
//  - K-loop must NOT fully unroll (R5: in-loop spill, FETCH 384MB). Guarded.
//  - manual prefetch is NOT load-bearing (R7: compiler sinks it). Omitted.
__global__ void __launch_bounds__(256, 2)
attn(const unsigned short* __restrict__ qbf, const unsigned short* __restrict__ ebf,
     const float* __restrict__ g, float2* __restrict__ part) {
    int tid  = threadIdx.x;
    int w    = tid >> 6;
    int lane = tid & 63;
    int quad = lane >> 4;
    int l15  = lane & 15;
    int head   = blockIdx.x & 7;
    int vslice = (blockIdx.x >> 3) & 31;   // 32 slices x 512 rows
    int qchunk = blockIdx.x >> 8;          // 2 chunks x 1024 q
    int qbase  = (qchunk * 4 + w) * 256;   // 256 q per wave

    // persistent Q B-frags: B[k=hs][n=q], lane: n=l15, k = kf*32 + quad*8 + j
    const short* qp = (const short*)qbf + (size_t)(head * QPH + qbase) * HS;
    bf16x8 qf[16][2];
    #pragma unroll
    for (int qt = 0; qt < 16; ++qt) {
        const short* qrow = qp + (qt * 16 + l15) * HS + quad * 8;
        qf[qt][0] = *(const bf16x8*)(qrow);
        qf[qt][1] = *(const bf16x8*)(qrow + 32);
    }

    const short* ep = (const short*)ebf + ((size_t)head * VOCAB + vslice * 512) * HS;
    const float* gp = g + head * VOCAB + vslice * 512;

    float num[16], den[16];
    #pragma unroll
    for (int qt = 0; qt < 16; ++qt) { num[qt] = 0.f; den[qt] = 0.f; }
    const f32x4 z = {0.f, 0.f, 0.f, 0.f};

    #pragma clang loop unroll(disable)
    for (int it = 0; it < 16; ++it) {
        int vb = it * 32;
        // A-frags direct from global (L2): A[m=v][k], lane: m=l15(+16), k=kf*32+quad*8+j
        const short* e0 = ep + (size_t)(vb + l15) * HS + quad * 8;
        const short* e1 = ep + (size_t)(vb + 16 + l15) * HS + quad * 8;
        bf16x8 a00 = *(const bf16x8*)(e0);
        bf16x8 a01 = *(const bf16x8*)(e0 + 32);
        bf16x8 a10 = *(const bf16x8*)(e1);
        bf16x8 a11 = *(const bf16x8*)(e1 + 32);
        f32x4 gv0 = *(const f32x4*)(gp + vb + quad * 4);
        f32x4 gv1 = *(const f32x4*)(gp + vb + 16 + quad * 4);
        #pragma unroll
        for (int qt = 0; qt < 16; ++qt) {
            f32x4 acc0 = __builtin_amdgcn_mfma_f32_16x16x32_bf16(a00, qf[qt][0], z, 0, 0, 0);
            acc0       = __builtin_amdgcn_mfma_f32_16x16x32_bf16(a01, qf[qt][1], acc0, 0, 0, 0);
            f32x4 acc1 = __builtin_amdgcn_mfma_f32_16x16x32_bf16(a10, qf[qt][0], z, 0, 0, 0);
            acc1       = __builtin_amdgcn_mfma_f32_16x16x32_bf16(a11, qf[qt][1], acc1, 0, 0, 0);
            // D layout: col=l15=q, row=quad*4+r = v-within-16-tile
            #pragma unroll
            for (int r = 0; r < 4; ++r) {
                float p0 = fexp2(acc0[r]);
                float p1 = fexp2(acc1[r]);
                den[qt] += p0 + p1;
                num[qt] += p0 * gv0[r] + p1 * gv1[r];
            }
        }
    }

    // reduce across quads (same l15 = same q)
    #pragma unroll
    for (int qt = 0; qt < 16; ++qt) {
        num[qt] += __shfl_xor(num[qt], 16); num[qt] += __shfl_xor(num[qt], 32);
        den[qt] += __shfl_xor(den[qt], 16); den[qt] += __shfl_xor(den[qt], 32);
    }
    // slotted partials (no atomics): part[vslice][head][q]; quad commits 4 tiles
    #pragma unroll
    for (int j = 0; j < 4; ++j) {
        int qt = quad * 4 + j;
        int qg = qbase + qt * 16 + l15;
        part[((size_t)vslice * NH + head) * QPH + qg] = make_float2(num[qt], den[qt]);
    }
}

// ---------------- Kernel 3: out[q] = dec_b + sum_n (sum_s num)/(sum_s den) -----------
__global__ void fin(const float2* __restrict__ part, const float* __restrict__ dec_b,
                    float* __restrict__ out) {
    int q = blockIdx.x * 256 + threadIdx.x;   // 0..2047
    float s = dec_b[0];
    #pragma unroll
    for (int n = 0; n < NH; ++n) {
        float nv = 0.f, dv = 0.f;
        #pragma unroll 4
        for (int sl = 0; sl < NSLICE; ++sl) {
            float2 nd = part[((size_t)sl * NH + n) * QPH + q];
            nv += nd.x; dv += nd.y;
        }
        s += nv / dv;
    }
    out[q] = s;
}

extern "C" void kernel_launch(void* const* d_in, const int* in_sizes, int n_in,
                              void* d_out, int out_size, void* d_ws, size_t ws_size,
                              hipStream_t stream) {
    const float* x     = (const float*)d_in[0];
    const float* emb   = (const float*)d_in[1];
    const float* enc_w = (const float*)d_in[2];
    const float* enc_b = (const float*)d_in[3];
    const float* ln_w  = (const float*)d_in[4];
    const float* ln_b  = (const float*)d_in[5];
    const float* dec_w = (const float*)d_in[6];
    const float* dec_b = (const float*)d_in[7];
    float* out = (float*)d_out;

    char* ws = (char*)d_ws;
    unsigned short* qbf  = (unsigned short*)(ws);                        // 2 MB
    unsigned short* ebf  = (unsigned short*)(ws + 2097152);              // 16 MB
    float*          g    = (float*)(ws + 2097152 + 16777216);            // 512 KB
    float2*         part = (float2*)(ws + 2097152 + 16777216 + 524288);  // 4 MB (32*8*2048 float2)

    hipLaunchKernelGGL(prep, dim3(12288), dim3(256), 0, stream,
                       x, emb, enc_w, enc_b, ln_w, ln_b, dec_w, qbf, ebf, g);
    hipLaunchKernelGGL(attn, dim3(512),  dim3(256), 0, stream, qbf, ebf, g, part);
    hipLaunchKernelGGL(fin,  dim3(8),    dim3(256), 0, stream, part, dec_b, out);
}

// Round 11
// 150.782 us; speedup vs baseline: 1.1135x; 1.1135x over previous
//
#include <hip/hip_runtime.h>
#include <hip/hip_bf16.h>
#include <math.h>

#define NH 8
#define HS 64
#define VOCAB 16384
#define QPH 2048                         // queries per head = b(4) * t(512)
#define NSLICE 32                        // vocab slices (512 rows each)
// fold 1/sqrt(512) * log2(e) into Q so the epilogue is p = exp2(score)
#define QSCALE (0.04419417382415922f * 1.4426950408889634f)

typedef __attribute__((ext_vector_type(8))) short bf16x8;
typedef __attribute__((ext_vector_type(4))) float f32x4;

static __device__ __forceinline__ unsigned short f2bf(float f) {
    __hip_bfloat16 h = __float2bfloat16(f);
    unsigned short u;
    __builtin_memcpy(&u, &h, 2);
    return u;
}

static __device__ __forceinline__ float fexp2(float x) {
#if __has_builtin(__builtin_amdgcn_exp2f)
    return __builtin_amdgcn_exp2f(x);     // v_exp_f32 directly
#else
    return __expf(x * 0.6931471805599453f);
#endif
}

// ---------------- Kernel 1a: eprep — E -> bf16 cast + g[n][v] = E[n][v,:].dec_w ------
__global__ void eprep(const float* __restrict__ emb, const float* __restrict__ dec_w,
                      unsigned short* __restrict__ ebf, float* __restrict__ g) {
    int i4  = blockIdx.x * 256 + threadIdx.x;   // float4 index, total 2097152
    int row = i4 >> 4;                          // (n, v) row
    int c   = i4 & 15;
    int n   = row >> 14;
    f32x4 v = ((const f32x4*)emb)[i4];
    ushort4 u = make_ushort4(f2bf(v.x), f2bf(v.y), f2bf(v.z), f2bf(v.w));
    ((ushort4*)ebf)[i4] = u;
    const float* dw = dec_w + n * 64 + c * 4;
    float p = v.x * dw[0] + v.y * dw[1] + v.z * dw[2] + v.w * dw[3];
    p += __shfl_xor(p, 1); p += __shfl_xor(p, 2);
    p += __shfl_xor(p, 4); p += __shfl_xor(p, 8);
    if (c == 0) g[row] = p;
}

// ---------------- Kernel 1b: qprep — Q = LayerNorm(enc(x)+PE) * QSCALE -> bf16 -------
__global__ void qprep(const float* __restrict__ x, const float* __restrict__ enc_w,
                      const float* __restrict__ enc_b, const float* __restrict__ ln_w,
                      const float* __restrict__ ln_b, unsigned short* __restrict__ qbf) {
    int row  = blockIdx.x * 4 + (threadIdx.x >> 6);  // n*2048 + q
    int h    = threadIdx.x & 63;
    int n = row >> 11;
    int q = row & 2047;
    int t = q & 511;
    float xv = x[q];
    int d = n * 64 + h;
    float h2  = (float)(h & ~1);
    float div = __expf(h2 * (-9.210340371976184f / 64.0f));
    float ang = (float)t * div;
    float pe  = (h & 1) ? __cosf(ang) : __sinf(ang);
    float v = xv * enc_w[d] + enc_b[d] + pe;
    float s = v;
    #pragma unroll
    for (int off = 1; off < 64; off <<= 1) s += __shfl_xor(s, off);
    float mu = s * (1.0f / 64.0f);
    float dd = v - mu;
    float s2 = dd * dd;
    #pragma unroll
    for (int off = 1; off < 64; off <<= 1) s2 += __shfl_xor(s2, off);
    float var = s2 * (1.0f / 64.0f);
    float y = dd * rsqrtf(var + 1e-5f) * ln_w[h] + ln_b[h];
    qbf[row * 64 + h] = f2bf(y * QSCALE);
}

// ---------------- Kernel 2: attn (R9 config — the proven optimum) --------------------
// grid 1024 = qchunk(4)*256 + vslice(32)*8 + head(8); block 256 (4 waves).
// blockIdx % 8 == head: each XCD's share touches ONE head's E (2MB < 4MB L2).
// Wave w: 128 q (8 MFMA q-tiles, Q persistent 64 VGPR) x 512-row vocab slice,
// trip-16 K-loop (unroll disabled).
// SCALING LAW (R3/R6/R8/R9/R10): duration ~= VALU-floor(~26us) + k * per-wave
// E traffic. q/wave sweet spot is 128: at 256 (R10) the compiler refuses to
// hold 128 VGPRs of Q (VGPR_Count=112 < 128) and re-loads Q in-loop — no gain.
// CODEGEN NOTES (hard-won):
//  - __launch_bounds__(256,3); tighter caps spill Q to scratch (R4: WRITE->1.5GB).
//  - K-loop must NOT fully unroll (R5: in-loop spill, FETCH 384MB). Guarded.
//  - manual prefetch is NOT load-bearing (R7: compiler sinks it). Omitted.
__global__ void __launch_bounds__(256, 3)
attn(const unsigned short* __restrict__ qbf, const unsigned short* __restrict__ ebf,
     const float* __restrict__ g, float2* __restrict__ part) {
    int tid  = threadIdx.x;
    int w    = tid >> 6;
    int lane = tid & 63;
    int quad = lane >> 4;
    int l15  = lane & 15;
    int head   = blockIdx.x & 7;
    int vslice = (blockIdx.x >> 3) & 31;   // 32 slices x 512 rows
    int qchunk = blockIdx.x >> 8;          // 4 chunks x 512 q
    int qbase  = (qchunk * 4 + w) * 128;   // 128 q per wave

    // persistent Q B-frags: B[k=hs][n=q], lane: n=l15, k = kf*32 + quad*8 + j
    const short* qp = (const short*)qbf + (size_t)(head * QPH + qbase) * HS;
    bf16x8 qf[8][2];
    #pragma unroll
    for (int qt = 0; qt < 8; ++qt) {
        const short* qrow = qp + (qt * 16 + l15) * HS + quad * 8;
        qf[qt][0] = *(const bf16x8*)(qrow);
        qf[qt][1] = *(const bf16x8*)(qrow + 32);
    }

    const short* ep = (const short*)ebf + ((size_t)head * VOCAB + vslice * 512) * HS;
    const float* gp = g + head * VOCAB + vslice * 512;

    float num[8] = {0.f, 0.f, 0.f, 0.f, 0.f, 0.f, 0.f, 0.f};
    float den[8] = {0.f, 0.f, 0.f, 0.f, 0.f, 0.f, 0.f, 0.f};
    const f32x4 z = {0.f, 0.f, 0.f, 0.f};

    #pragma clang loop unroll(disable)
    for (int it = 0; it < 16; ++it) {
        int vb = it * 32;
        // A-frags direct from global (L2): A[m=v][k], lane: m=l15(+16), k=kf*32+quad*8+j
        const short* e0 = ep + (size_t)(vb + l15) * HS + quad * 8;
        const short* e1 = ep + (size_t)(vb + 16 + l15) * HS + quad * 8;
        bf16x8 a00 = *(const bf16x8*)(e0);
        bf16x8 a01 = *(const bf16x8*)(e0 + 32);
        bf16x8 a10 = *(const bf16x8*)(e1);
        bf16x8 a11 = *(const bf16x8*)(e1 + 32);
        f32x4 gv0 = *(const f32x4*)(gp + vb + quad * 4);
        f32x4 gv1 = *(const f32x4*)(gp + vb + 16 + quad * 4);
        #pragma unroll
        for (int qt = 0; qt < 8; ++qt) {
            f32x4 acc0 = __builtin_amdgcn_mfma_f32_16x16x32_bf16(a00, qf[qt][0], z, 0, 0, 0);
            acc0       = __builtin_amdgcn_mfma_f32_16x16x32_bf16(a01, qf[qt][1], acc0, 0, 0, 0);
            f32x4 acc1 = __builtin_amdgcn_mfma_f32_16x16x32_bf16(a10, qf[qt][0], z, 0, 0, 0);
            acc1       = __builtin_amdgcn_mfma_f32_16x16x32_bf16(a11, qf[qt][1], acc1, 0, 0, 0);
            // D layout: col=l15=q, row=quad*4+r = v-within-16-tile
            #pragma unroll
            for (int r = 0; r < 4; ++r) {
                float p0 = fexp2(acc0[r]);
                float p1 = fexp2(acc1[r]);
                den[qt] += p0 + p1;
                num[qt] += p0 * gv0[r] + p1 * gv1[r];
            }
        }
    }

    // reduce across quads (same l15 = same q)
    #pragma unroll
    for (int qt = 0; qt < 8; ++qt) {
        num[qt] += __shfl_xor(num[qt], 16); num[qt] += __shfl_xor(num[qt], 32);
        den[qt] += __shfl_xor(den[qt], 16); den[qt] += __shfl_xor(den[qt], 32);
    }
    // slotted partials (no atomics): part[vslice][head][q]; quad commits 2 tiles
    #pragma unroll
    for (int j = 0; j < 2; ++j) {
        int qt = quad * 2 + j;
        int qg = qbase + qt * 16 + l15;
        part[((size_t)vslice * NH + head) * QPH + qg] = make_float2(num[qt], den[qt]);
    }
}

// ---------------- Kernel 3: fin — parallel over (n,q), LDS reduce over n -------------
// grid 64 x 256: thread t of block b -> q = b*32 + (t&31), n = t>>5.
// Each thread sums its (n,q) over 32 slices, LDS-reduces the 8 heads per q.
// (old fin: grid 8, 256 serial loads/thread -> suspected 20-40us latency hole)
__global__ void fin(const float2* __restrict__ part, const float* __restrict__ dec_b,
                    float* __restrict__ out) {
    __shared__ float red[8][32];
    int t  = threadIdx.x;
    int ql = t & 31;
    int n  = t >> 5;
    int q  = blockIdx.x * 32 + ql;
    float nv = 0.f, dv = 0.f;
    #pragma unroll 8
    for (int sl = 0; sl < NSLICE; ++sl) {
        float2 nd = part[((size_t)sl * NH + n) * QPH + q];
        nv += nd.x; dv += nd.y;
    }
    red[n][ql] = nv / dv;
    __syncthreads();
    if (t < 32) {
        float s = dec_b[0];
        #pragma unroll
        for (int m = 0; m < NH; ++m) s += red[m][t];
        out[q] = s;
    }
}

extern "C" void kernel_launch(void* const* d_in, const int* in_sizes, int n_in,
                              void* d_out, int out_size, void* d_ws, size_t ws_size,
                              hipStream_t stream) {
    const float* x     = (const float*)d_in[0];
    const float* emb   = (const float*)d_in[1];
    const float* enc_w = (const float*)d_in[2];
    const float* enc_b = (const float*)d_in[3];
    const float* ln_w  = (const float*)d_in[4];
    const float* ln_b  = (const float*)d_in[5];
    const float* dec_w = (const float*)d_in[6];
    const float* dec_b = (const float*)d_in[7];
    float* out = (float*)d_out;

    char* ws = (char*)d_ws;
    unsigned short* qbf  = (unsigned short*)(ws);                        // 2 MB
    unsigned short* ebf  = (unsigned short*)(ws + 2097152);              // 16 MB
    float*          g    = (float*)(ws + 2097152 + 16777216);            // 512 KB
    float2*         part = (float2*)(ws + 2097152 + 16777216 + 524288);  // 4 MB (32*8*2048 float2)

    hipLaunchKernelGGL(eprep, dim3(8192), dim3(256), 0, stream, emb, dec_w, ebf, g);
    hipLaunchKernelGGL(qprep, dim3(4096), dim3(256), 0, stream, x, enc_w, enc_b, ln_w, ln_b, qbf);
    hipLaunchKernelGGL(attn,  dim3(1024), dim3(256), 0, stream, qbf, ebf, g, part);
    hipLaunchKernelGGL(fin,   dim3(64),   dim3(256), 0, stream, part, dec_b, out);
}